// Round 14
// baseline (790.681 us; speedup 1.0000x reference)
//
#include <hip/hip_runtime.h>
#include <stdint.h>

// ---- Problem constants -------------------------------------------------
#define DIM   1536
#define NQ    6272      // 8 * 28 * 28 queries
#define NQP   6400      // padded to 25 * 256
#define NB    50000     // bank rows
#define NBP2  50176     // padded to 196 * 256
#define MT2   25
#define NT2   196
#define GRID2 (MT2 * NT2)
#define NKT   24        // 1536 / 64 K-tiles
#define NIT   12        // NKT / 2 iterations
#define NPIX  (8 * 224 * 224)

typedef float f32x4 __attribute__((ext_vector_type(4)));
typedef int   i32x4 __attribute__((ext_vector_type(4)));
typedef __attribute__((address_space(3))) signed char lds_i8;

__device__ inline void gll16(const signed char* g, signed char* l) {
  __builtin_amdgcn_global_load_lds(
      (const __attribute__((address_space(1))) uint32_t*)g,
      (__attribute__((address_space(3))) uint32_t*)l, 16, 0, 0);
}

// ---- init: minbits = +inf, image scores = 0 ---------------------------
__global__ void init_kernel(uint32_t* __restrict__ minbits, float* __restrict__ out_scores) {
  int i = blockIdx.x * 256 + threadIdx.x;
  if (i < NQP) minbits[i] = 0x7F800000u;   // +inf
  if (i < 8)   out_scores[i] = 0.0f;
}

// ---- fp32 -> int8 row quantization + fp32 row norms + scales ----------
// one wave per row; scale = maxabs/127; norm from ORIGINAL fp32 values.
__global__ void quant_rows(const float* __restrict__ src, signed char* __restrict__ dst,
                           float* __restrict__ norms, float* __restrict__ scales,
                           int nsrc, int ndst) {
  int row  = blockIdx.x * 4 + (threadIdx.x >> 6);
  int lane = threadIdx.x & 63;
  if (row >= ndst) return;
  uint32_t* drow = (uint32_t*)(dst + (size_t)row * DIM);
  if (row < nsrc) {
    const float4* s = (const float4*)(src + (size_t)row * DIM);
    float4 v[6]; float ns = 0.f, mx = 0.f;
#pragma unroll
    for (int i = 0; i < 6; ++i) {
      v[i] = s[lane + 64 * i];
      ns += v[i].x * v[i].x + v[i].y * v[i].y + v[i].z * v[i].z + v[i].w * v[i].w;
      mx = fmaxf(mx, fmaxf(fmaxf(fabsf(v[i].x), fabsf(v[i].y)),
                           fmaxf(fabsf(v[i].z), fabsf(v[i].w))));
    }
#pragma unroll
    for (int off = 32; off >= 1; off >>= 1) {
      ns += __shfl_xor(ns, off);
      mx = fmaxf(mx, __shfl_xor(mx, off));
    }
    float inv = (mx > 0.f) ? 127.0f / mx : 0.f;
#pragma unroll
    for (int i = 0; i < 6; ++i) {
      int a = max(-127, min(127, __float2int_rn(v[i].x * inv)));
      int b = max(-127, min(127, __float2int_rn(v[i].y * inv)));
      int c = max(-127, min(127, __float2int_rn(v[i].z * inv)));
      int d = max(-127, min(127, __float2int_rn(v[i].w * inv)));
      drow[lane + 64 * i] = (uint32_t)(a & 255) | ((uint32_t)(b & 255) << 8) |
                            ((uint32_t)(c & 255) << 16) | ((uint32_t)(d & 255) << 24);
    }
    if (lane == 0) { norms[row] = ns; scales[row] = mx * (1.0f / 127.0f); }
  } else {
#pragma unroll
    for (int i = 0; i < 6; ++i) drow[lane + 64 * i] = 0u;
    if (lane == 0) { norms[row] = 1e30f; scales[row] = 0.f; }   // pad never wins
  }
}

// ---- fused 256x256 int8 GEMM + column-min -----------------------------
// BM=BN=256, BK=64, 512 thr = 8 waves (2M x 4N), per-wave 128x64 out.
// mfma_i32_16x16x64_i8: K=64/instr -> 32 MFMA/tile/wave.
// FRAGMENT-BLOCK LDS layout: each 16-row x 64B fragment is a contiguous
// 1KB block ordered [k16][row][16B], so a wave's fragment read is lane ->
// slot LINEAR (addr = block + lane*16): zero bank conflicts (fix for
// R13's 4.5e7: 64B rows gave slot%8 = f(lr&1,k16) -> 8-way alias).
// Staging: linear gll16 dest; per-lane global source re-laid-out.
// R9 counted-lgkm skeleton: reads issued >=1 phase ahead, LGKM(n=just-
// issued) drains only older; gates (VM2) pre-barrier, reads post-barrier.
#define BAR   do { asm volatile("s_barrier" ::: "memory"); \
                   __builtin_amdgcn_sched_barrier(0); } while(0)
#define LGKM(n) do { asm volatile("s_waitcnt lgkmcnt(" #n ")" ::: "memory"); \
                     __builtin_amdgcn_sched_barrier(0); } while(0)
#define VM0   asm volatile("s_waitcnt vmcnt(0)" ::: "memory")
#define VM2   asm volatile("s_waitcnt vmcnt(2)" ::: "memory")
#define VM4   asm volatile("s_waitcnt vmcnt(4)" ::: "memory")
#define PHI   __builtin_amdgcn_s_setprio(1)
#define PLO   __builtin_amdgcn_s_setprio(0)

#define DSR(dst, base, imm) \
  asm volatile("ds_read_b128 %0, %1 offset:%2" : "=v"(dst) : "v"(base), "i"(imm))

// A quad: fragment blocks wm*8 + quad*4 + {0..3}, each 1KB, lane-linear
#define READ_AQ(dst, bufI, quad) do { \
  DSR(dst[0], aOff, (bufI) * 16384 + (quad) * 4096 + 0);    \
  DSR(dst[1], aOff, (bufI) * 16384 + (quad) * 4096 + 1024); \
  DSR(dst[2], aOff, (bufI) * 16384 + (quad) * 4096 + 2048); \
  DSR(dst[3], aOff, (bufI) * 16384 + (quad) * 4096 + 3072); \
} while(0)

// B quad: fragment blocks bh*8 + bq*4 + {0..3}
#define READ_B4(dst, bufI) do { \
  DSR(dst[0], bOff, (bufI) * 16384 + 0);    \
  DSR(dst[1], bOff, (bufI) * 16384 + 1024); \
  DSR(dst[2], bOff, (bufI) * 16384 + 2048); \
  DSR(dst[3], bOff, (bufI) * 16384 + 3072); \
} while(0)

// 8 MFMA: m-pair (mb, mb+1) x 4 n, K=64
#define MFMA8(mb, x0, x1, b4) do { \
  _Pragma("unroll") for (int n_ = 0; n_ < 4; ++n_) { \
    acc[(mb)][n_]     = __builtin_amdgcn_mfma_i32_16x16x64_i8( \
      __builtin_bit_cast(i32x4, (x0)), __builtin_bit_cast(i32x4, b4[n_]), acc[(mb)][n_], 0, 0, 0); \
    acc[(mb) + 1][n_] = __builtin_amdgcn_mfma_i32_16x16x64_i8( \
      __builtin_bit_cast(i32x4, (x1)), __builtin_bit_cast(i32x4, b4[n_]), acc[(mb) + 1][n_], 0, 0, 0); \
  } \
} while(0)

// stage one 256x64 i8 tile (16 KB) = 2 gll16/thread; dest linear, source
// per-lane in fragment-block order: thread t -> block t>>6, k16=(t>>4)&3,
// row=(t&15)  =>  global row (t>>6)*16+(t&15), col ((t>>4)&3)*16.
#define STAGE_A(bufI, ktc) do { \
  const signed char* _g = gA + (size_t)srow * DIM + (ktc) + scol; \
  gll16(_g,                      &sA[bufI][sdst]); \
  gll16(_g + (size_t)128 * DIM,  &sA[bufI][8192 + sdst]); \
} while(0)

#define STAGE_B(bufI, ktc) do { \
  const signed char* _g = gB + (size_t)srow * DIM + (ktc) + scol; \
  gll16(_g,                      &sB[bufI][sdst]); \
  gll16(_g + (size_t)128 * DIM,  &sB[bufI][8192 + sdst]); \
} while(0)

// iter i: tiles t0=2i (buf0, ph1-4) + t1 (buf1, ph5-8); T0 = i*128 (cols).
// Reads: ph1 aQ(buf0,q1); ph3 aP(buf1,q0)+bO(buf1); ph5 aQ(buf1,q1);
//        ph7 aP(buf0',q0)+bE(buf0')  [next tiles].
// Stages: ph2 B(t2), ph4 A(t2), ph6 B(t3), ph8 A(t3).
// Gates: ph2 VM2 (keeps own stage, retires t1's A+B -> ph3 reads safe);
//        ph6 VM2 (retires t2's A+B -> ph7 reads safe). Stage->gate->BAR.
// WAR: every staged region's readers drained at an earlier phase's LGKM
// + barrier (verified per-slot). Tail: VM0 at ph2, LGKM(0) at ph7.
#define ITER(T0, SN, RD) do { \
  /* ph1 */ READ_AQ(aQ, 0, 1); \
    LGKM(4); BAR; PHI; MFMA8(0, aP[0], aP[1], bE); PLO; \
  /* ph2 */ if (SN) { STAGE_B(0, (T0) + 128); VM2; } else { VM0; } \
    BAR; PHI; MFMA8(2, aP[2], aP[3], bE); PLO; \
  /* ph3 */ READ_AQ(aP, 1, 0); READ_B4(bO, 1); \
    LGKM(8); BAR; PHI; MFMA8(4, aQ[0], aQ[1], bE); PLO; \
  /* ph4 */ if (SN) STAGE_A(0, (T0) + 128); \
    BAR; PHI; MFMA8(6, aQ[2], aQ[3], bE); PLO; \
  /* ph5 */ READ_AQ(aQ, 1, 1); \
    LGKM(4); BAR; PHI; MFMA8(0, aP[0], aP[1], bO); PLO; \
  /* ph6 */ if (SN) { STAGE_B(1, (T0) + 192); VM2; } \
    BAR; PHI; MFMA8(2, aP[2], aP[3], bO); PLO; \
  /* ph7 */ if (RD) { READ_AQ(aP, 0, 0); READ_B4(bE, 0); LGKM(8); } else { LGKM(0); } \
    BAR; PHI; MFMA8(4, aQ[0], aQ[1], bO); PLO; \
  /* ph8 */ if (SN) STAGE_A(1, (T0) + 192); \
    BAR; PHI; MFMA8(6, aQ[2], aQ[3], bO); PLO; \
} while(0)

__global__ __launch_bounds__(512, 2)
void gemm_min8(const signed char* __restrict__ fA, const signed char* __restrict__ bB,
               const float* __restrict__ bn, const float* __restrict__ bscale,
               const float* __restrict__ qscale, uint32_t* __restrict__ minbits) {
  __shared__ __align__(16) signed char sA[2][16384];   // [buf][16 frag-blocks x 1KB] = 32 KiB
  __shared__ __align__(16) signed char sB[2][16384];   // 32 KiB

  const int nwg = GRID2;
  int bid = blockIdx.x;
  const int qch = nwg >> 3, rch = nwg & 7;
  int xcd = bid & 7, loc = bid >> 3;
  int swz = (xcd < rch ? xcd * (qch + 1) : rch * (qch + 1) + (xcd - rch) * qch) + loc;
  int mt = swz % MT2;            // M-fast: consecutive blocks share the B (bank) panel
  int nt = swz / MT2;

  int tid = threadIdx.x;
  int lane = tid & 63, wave = tid >> 6;
  int wm = wave >> 2, wn = wave & 3, bq = wn & 1, bh = wn >> 1;
  int lr = lane & 15;

  const signed char* gA = fA + (size_t)(mt * 256) * DIM;
  const signed char* gB = bB + (size_t)(nt * 256) * DIM;

  // staging source (fragment-block order) + linear dest
  int srow = (tid >> 6) * 16 + (tid & 15);   // block row-base + row
  int scol = ((tid >> 4) & 3) * 16;          // k16 slot
  int sdst = tid * 16;                       // byte offset in 8 KB half

  // fragment-block read bases: block + lane*16 (lane-linear, conflict-free)
  uint32_t aOff = (uint32_t)(uintptr_t)(lds_i8*)&sA[0][(wm * 8) * 1024 + lane * 16];
  uint32_t bOff = (uint32_t)(uintptr_t)(lds_i8*)&sB[0][(bh * 8 + bq * 4) * 1024 + lane * 16];

  i32x4 acc[8][4] = {};
  f32x4 aP[4], aQ[4], bE[4], bO[4];

  // prologue: tiles 0 (buf0) + 1 (buf1) staged; retire tile0 (VM4 keeps
  // tile1's 4 in flight, gated at first ph2); publish; pre-read ph1 frags.
  STAGE_A(0, 0); STAGE_B(0, 0);
  STAGE_A(1, 64); STAGE_B(1, 64);
  VM4; BAR;
  READ_AQ(aP, 0, 0); READ_B4(bE, 0);   // drained by ph1's LGKM(4)

#pragma unroll 1
  for (int i = 0; i < NIT - 1; ++i) {
    ITER(i * 128, 1, 1);
  }
  ITER((NIT - 1) * 128, 0, 0);   // tiles 22,23: no stages/read-ahead

  // epilogue: per-row min over this tile's 256 cols of (bn - 2*sq*sb*idot)
  float bnv[4], bsv[4];
#pragma unroll
  for (int n_ = 0; n_ < 4; ++n_) {
    int col = nt * 256 + wn * 64 + n_ * 16 + lr;
    bnv[n_] = bn[col];
    bsv[n_] = 2.0f * bscale[col];
  }
  int qbase = mt * 256 + wm * 128;
#pragma unroll
  for (int m_ = 0; m_ < 8; ++m_) {
    f32x4 sq = *(const f32x4*)&qscale[qbase + m_ * 16 + (lane >> 4) * 4];
#pragma unroll
    for (int r = 0; r < 4; ++r) {
      float sqr = sq[r];
      float v =          bnv[0] - bsv[0] * sqr * (float)acc[m_][0][r];
      v = fminf(v, bnv[1] - bsv[1] * sqr * (float)acc[m_][1][r]);
      v = fminf(v, bnv[2] - bsv[2] * sqr * (float)acc[m_][2][r]);
      v = fminf(v, bnv[3] - bsv[3] * sqr * (float)acc[m_][3][r]);
      // C/D layout (shape-determined): col = lane&15, row = (lane>>4)*4+r
      v = fminf(v, __shfl_xor(v, 1));
      v = fminf(v, __shfl_xor(v, 2));
      v = fminf(v, __shfl_xor(v, 4));
      v = fminf(v, __shfl_xor(v, 8));
      if (lr == 0) {
        int q = qbase + m_ * 16 + (lane >> 4) * 4 + r;
        atomicMin(&minbits[q], __float_as_uint(v));  // positive floats: uint order == float order
      }
    }
  }
}

// ---- patch scores + per-image max -------------------------------------
__global__ void scores_kernel(const uint32_t* __restrict__ minbits, const float* __restrict__ qn,
                              float* __restrict__ ps, float* __restrict__ img) {
  int q = blockIdx.x * 256 + threadIdx.x;
  if (q >= NQ) return;
  float s = __uint_as_float(minbits[q]) + qn[q];
  ps[q] = s;
  atomicMax((uint32_t*)&img[q / 784], __float_as_uint(s));  // scores > 0
}

// ---- bilinear 28x28 -> 224x224 (half-pixel centers, edge clamp) -------
__global__ void resize_kernel(const float* __restrict__ ps, float* __restrict__ masks) {
  int idx = blockIdx.x * 256 + threadIdx.x;
  if (idx >= NPIX) return;
  int b   = idx / (224 * 224);
  int rem = idx - b * (224 * 224);
  int oy  = rem / 224;
  int ox  = rem - oy * 224;
  float sy = (oy + 0.5f) * 0.125f - 0.5f;
  float sx = (ox + 0.5f) * 0.125f - 0.5f;
  float fy0 = floorf(sy), fx0 = floorf(sx);
  int y0 = (int)fy0, x0 = (int)fx0;
  float fy = sy - fy0, fx = sx - fx0;
  int y0c = min(max(y0, 0), 27),     y1c = min(max(y0 + 1, 0), 27);
  int x0c = min(max(x0, 0), 27),     x1c = min(max(x0 + 1, 0), 27);
  const float* p = ps + b * 784;
  float top = p[y0c * 28 + x0c] * (1.f - fx) + p[y0c * 28 + x1c] * fx;
  float bot = p[y1c * 28 + x0c] * (1.f - fx) + p[y1c * 28 + x1c] * fx;
  masks[idx] = top * (1.f - fy) + bot * fy;
}

// ---- host launch -------------------------------------------------------
extern "C" void kernel_launch(void* const* d_in, const int* in_sizes, int n_in,
                              void* d_out, int out_size, void* d_ws, size_t ws_size,
                              hipStream_t stream) {
  const float* features = (const float*)d_in[0];   // [6272, 1536]
  const float* bank     = (const float*)d_in[1];   // [50000, 1536]

  char* ws = (char*)d_ws;
  size_t off = 0;
  signed char* bankQ = (signed char*)(ws + off); off += (size_t)NBP2 * DIM;   // 77.1 MB
  signed char* featQ = (signed char*)(ws + off); off += (size_t)NQP * DIM;    //  9.8 MB
  float*    bn      = (float*)(ws + off);    off += (size_t)NBP2 * 4;
  float*    qn      = (float*)(ws + off);    off += (size_t)NQP * 4;
  float*    bscale  = (float*)(ws + off);    off += (size_t)NBP2 * 4;
  float*    qscale  = (float*)(ws + off);    off += (size_t)NQP * 4;
  uint32_t* minbits = (uint32_t*)(ws + off); off += (size_t)NQP * 4;
  float*    ps      = (float*)(ws + off);    off += (size_t)NQ * 4;

  float* out_scores = (float*)d_out;       // [8]
  float* masks      = out_scores + 8;      // [8,224,224]

  hipLaunchKernelGGL(init_kernel, dim3(25), dim3(256), 0, stream, minbits, out_scores);
  hipLaunchKernelGGL(quant_rows, dim3(NBP2 / 4), dim3(256), 0, stream, bank, bankQ, bn, bscale, NB, NBP2);
  hipLaunchKernelGGL(quant_rows, dim3(NQP / 4), dim3(256), 0, stream, features, featQ, qn, qscale, NQ, NQP);
  hipLaunchKernelGGL(gemm_min8, dim3(GRID2), dim3(512), 0, stream, featQ, bankQ, bn, bscale, qscale, minbits);
  hipLaunchKernelGGL(scores_kernel, dim3(25), dim3(256), 0, stream, minbits, qn, ps, out_scores);
  hipLaunchKernelGGL(resize_kernel, dim3((NPIX + 255) / 256), dim3(256), 0, stream, ps, masks);
}

// Round 15
// 704.397 us; speedup vs baseline: 1.1225x; 1.1225x over previous
//
#include <hip/hip_runtime.h>
#include <stdint.h>

// ---- Problem constants -------------------------------------------------
#define DIM   1536
#define NQ    6272      // 8 * 28 * 28 queries
#define NQP   6400      // padded to 25 * 256
#define NB    50000     // bank rows
#define NBP2  50176     // padded to 196 * 256
#define MT2   25
#define NT2   196
#define GRID2 (MT2 * NT2)
#define NKT   24        // 1536 / 64 K-tiles
#define NIT   12        // NKT / 2 iterations
#define NPIX  (8 * 224 * 224)

typedef float f32x4 __attribute__((ext_vector_type(4)));
typedef int   i32x4 __attribute__((ext_vector_type(4)));
typedef __attribute__((address_space(3))) signed char lds_i8;

__device__ inline void gll16(const signed char* g, signed char* l) {
  __builtin_amdgcn_global_load_lds(
      (const __attribute__((address_space(1))) uint32_t*)g,
      (__attribute__((address_space(3))) uint32_t*)l, 16, 0, 0);
}

// ---- init: minbits = +inf, image scores = 0 ---------------------------
__global__ void init_kernel(uint32_t* __restrict__ minbits, float* __restrict__ out_scores) {
  int i = blockIdx.x * 256 + threadIdx.x;
  if (i < NQP) minbits[i] = 0x7F800000u;   // +inf
  if (i < 8)   out_scores[i] = 0.0f;
}

// ---- fp32 -> int8 row quantization + fp32 row norms + scales ----------
// one wave per row; scale = maxabs/127; norm from ORIGINAL fp32 values.
__global__ void quant_rows(const float* __restrict__ src, signed char* __restrict__ dst,
                           float* __restrict__ norms, float* __restrict__ scales,
                           int nsrc, int ndst) {
  int row  = blockIdx.x * 4 + (threadIdx.x >> 6);
  int lane = threadIdx.x & 63;
  if (row >= ndst) return;
  uint32_t* drow = (uint32_t*)(dst + (size_t)row * DIM);
  if (row < nsrc) {
    const float4* s = (const float4*)(src + (size_t)row * DIM);
    float4 v[6]; float ns = 0.f, mx = 0.f;
#pragma unroll
    for (int i = 0; i < 6; ++i) {
      v[i] = s[lane + 64 * i];
      ns += v[i].x * v[i].x + v[i].y * v[i].y + v[i].z * v[i].z + v[i].w * v[i].w;
      mx = fmaxf(mx, fmaxf(fmaxf(fabsf(v[i].x), fabsf(v[i].y)),
                           fmaxf(fabsf(v[i].z), fabsf(v[i].w))));
    }
#pragma unroll
    for (int off = 32; off >= 1; off >>= 1) {
      ns += __shfl_xor(ns, off);
      mx = fmaxf(mx, __shfl_xor(mx, off));
    }
    float inv = (mx > 0.f) ? 127.0f / mx : 0.f;
#pragma unroll
    for (int i = 0; i < 6; ++i) {
      int a = max(-127, min(127, __float2int_rn(v[i].x * inv)));
      int b = max(-127, min(127, __float2int_rn(v[i].y * inv)));
      int c = max(-127, min(127, __float2int_rn(v[i].z * inv)));
      int d = max(-127, min(127, __float2int_rn(v[i].w * inv)));
      drow[lane + 64 * i] = (uint32_t)(a & 255) | ((uint32_t)(b & 255) << 8) |
                            ((uint32_t)(c & 255) << 16) | ((uint32_t)(d & 255) << 24);
    }
    if (lane == 0) { norms[row] = ns; scales[row] = mx * (1.0f / 127.0f); }
  } else {
#pragma unroll
    for (int i = 0; i < 6; ++i) drow[lane + 64 * i] = 0u;
    if (lane == 0) { norms[row] = 1e30f; scales[row] = 0.f; }   // pad never wins
  }
}

// ---- fused 256x256 int8 GEMM + column-min -----------------------------
// BM=BN=256, BK=64, 512 thr = 8 waves (2M x 4N), per-wave 128x64 out.
// mfma_i32_16x16x64_i8: K=64/instr -> 32 MFMA/tile/wave.
// Row-major 64B-row LDS tiles (R13) + CHUNK-XOR swizzle (rule 21 pattern):
// LDS (row r, 16B-slot c) holds data chunk c ^ ((r>>1)&3). Staging keeps
// R13's coalesced 64B segments (chunks permuted within segment); reads use
// addr = r*64 + ((k16 ^ ((r>>1)&3))*16) -> per-16-lane quarter each bank
// group gets exactly 2 lanes (free, m136). Fixes R13's 8-way conflicts
// (4.5e7) without R14's scattered staging.
// R9 counted-lgkm skeleton: reads issued >=1 phase ahead, LGKM(n=just-
// issued) drains only older; gates (VM2) pre-barrier, reads post-barrier.
#define BAR   do { asm volatile("s_barrier" ::: "memory"); \
                   __builtin_amdgcn_sched_barrier(0); } while(0)
#define LGKM(n) do { asm volatile("s_waitcnt lgkmcnt(" #n ")" ::: "memory"); \
                     __builtin_amdgcn_sched_barrier(0); } while(0)
#define VM0   asm volatile("s_waitcnt vmcnt(0)" ::: "memory")
#define VM2   asm volatile("s_waitcnt vmcnt(2)" ::: "memory")
#define VM4   asm volatile("s_waitcnt vmcnt(4)" ::: "memory")
#define PHI   __builtin_amdgcn_s_setprio(1)
#define PLO   __builtin_amdgcn_s_setprio(0)

#define DSR(dst, base, imm) \
  asm volatile("ds_read_b128 %0, %1 offset:%2" : "=v"(dst) : "v"(base), "i"(imm))

// A quad: m-fragments quad*4..quad*4+3 (rows m*16+lr), 1024B apart
#define READ_AQ(dst, bufI, quad) do { \
  DSR(dst[0], aOff, (bufI) * 16384 + (quad) * 4096 + 0);    \
  DSR(dst[1], aOff, (bufI) * 16384 + (quad) * 4096 + 1024); \
  DSR(dst[2], aOff, (bufI) * 16384 + (quad) * 4096 + 2048); \
  DSR(dst[3], aOff, (bufI) * 16384 + (quad) * 4096 + 3072); \
} while(0)

// B quad: n-fragments 0..3 (rows bh*128+bq*64+n*16+lr)
#define READ_B4(dst, bufI) do { \
  DSR(dst[0], bOff, (bufI) * 16384 + 0);    \
  DSR(dst[1], bOff, (bufI) * 16384 + 1024); \
  DSR(dst[2], bOff, (bufI) * 16384 + 2048); \
  DSR(dst[3], bOff, (bufI) * 16384 + 3072); \
} while(0)

// 8 MFMA: m-pair (mb, mb+1) x 4 n, K=64
#define MFMA8(mb, x0, x1, b4) do { \
  _Pragma("unroll") for (int n_ = 0; n_ < 4; ++n_) { \
    acc[(mb)][n_]     = __builtin_amdgcn_mfma_i32_16x16x64_i8( \
      __builtin_bit_cast(i32x4, (x0)), __builtin_bit_cast(i32x4, b4[n_]), acc[(mb)][n_], 0, 0, 0); \
    acc[(mb) + 1][n_] = __builtin_amdgcn_mfma_i32_16x16x64_i8( \
      __builtin_bit_cast(i32x4, (x1)), __builtin_bit_cast(i32x4, b4[n_]), acc[(mb) + 1][n_], 0, 0, 0); \
  } \
} while(0)

// stage one 256x64 i8 tile (16 KB) = 2 gll16/thread; dest linear,
// source: row = tid>>2 (coalesced 64B segments), chunk permuted by
// (tid&3) ^ ((tid>>3)&3) = c ^ ((row>>1)&3). Row+128 has same xor term.
#define STAGE_A(bufI, ktc) do { \
  const signed char* _g = gA + (size_t)srow * DIM + (ktc) + scol; \
  gll16(_g,                      &sA[bufI][sdst]); \
  gll16(_g + (size_t)128 * DIM,  &sA[bufI][8192 + sdst]); \
} while(0)

#define STAGE_B(bufI, ktc) do { \
  const signed char* _g = gB + (size_t)srow * DIM + (ktc) + scol; \
  gll16(_g,                      &sB[bufI][sdst]); \
  gll16(_g + (size_t)128 * DIM,  &sB[bufI][8192 + sdst]); \
} while(0)

// iter i: tiles t0=2i (buf0, ph1-4) + t1 (buf1, ph5-8); T0 = i*128 (cols).
// Reads: ph1 aQ(buf0,q1); ph3 aP(buf1,q0)+bO(buf1); ph5 aQ(buf1,q1);
//        ph7 aP(buf0',q0)+bE(buf0')  [next tiles].
// Stages: ph2 B(t2), ph4 A(t2), ph6 B(t3), ph8 A(t3).
// Gates: ph2 VM2 (keeps own stage, retires t1's A+B -> ph3 reads safe);
//        ph6 VM2 (retires t2's A+B -> ph7 reads safe). Stage->gate->BAR.
// WAR: every staged region's readers drained at an earlier phase's LGKM
// + barrier (verified per-slot). Tail: VM0 at ph2, LGKM(0) at ph7.
#define ITER(T0, SN, RD) do { \
  /* ph1 */ READ_AQ(aQ, 0, 1); \
    LGKM(4); BAR; PHI; MFMA8(0, aP[0], aP[1], bE); PLO; \
  /* ph2 */ if (SN) { STAGE_B(0, (T0) + 128); VM2; } else { VM0; } \
    BAR; PHI; MFMA8(2, aP[2], aP[3], bE); PLO; \
  /* ph3 */ READ_AQ(aP, 1, 0); READ_B4(bO, 1); \
    LGKM(8); BAR; PHI; MFMA8(4, aQ[0], aQ[1], bE); PLO; \
  /* ph4 */ if (SN) STAGE_A(0, (T0) + 128); \
    BAR; PHI; MFMA8(6, aQ[2], aQ[3], bE); PLO; \
  /* ph5 */ READ_AQ(aQ, 1, 1); \
    LGKM(4); BAR; PHI; MFMA8(0, aP[0], aP[1], bO); PLO; \
  /* ph6 */ if (SN) { STAGE_B(1, (T0) + 192); VM2; } \
    BAR; PHI; MFMA8(2, aP[2], aP[3], bO); PLO; \
  /* ph7 */ if (RD) { READ_AQ(aP, 0, 0); READ_B4(bE, 0); LGKM(8); } else { LGKM(0); } \
    BAR; PHI; MFMA8(4, aQ[0], aQ[1], bO); PLO; \
  /* ph8 */ if (SN) STAGE_A(1, (T0) + 192); \
    BAR; PHI; MFMA8(6, aQ[2], aQ[3], bO); PLO; \
} while(0)

__global__ __launch_bounds__(512, 2)
void gemm_min8(const signed char* __restrict__ fA, const signed char* __restrict__ bB,
               const float* __restrict__ bn, const float* __restrict__ bscale,
               const float* __restrict__ qscale, uint32_t* __restrict__ minbits) {
  __shared__ __align__(16) signed char sA[2][16384];   // [buf][256 rows][64] = 32 KiB
  __shared__ __align__(16) signed char sB[2][16384];   // 32 KiB

  const int nwg = GRID2;
  int bid = blockIdx.x;
  const int qch = nwg >> 3, rch = nwg & 7;
  int xcd = bid & 7, loc = bid >> 3;
  int swz = (xcd < rch ? xcd * (qch + 1) : rch * (qch + 1) + (xcd - rch) * qch) + loc;
  int mt = swz % MT2;            // M-fast: consecutive blocks share the B (bank) panel
  int nt = swz / MT2;

  int tid = threadIdx.x;
  int lane = tid & 63, wave = tid >> 6;
  int wm = wave >> 2, wn = wave & 3, bq = wn & 1, bh = wn >> 1;
  int lr = lane & 15, k16 = lane >> 4;

  const signed char* gA = fA + (size_t)(mt * 256) * DIM;
  const signed char* gB = bB + (size_t)(nt * 256) * DIM;

  // staging: row = tid>>2 (coalesced), chunk xor-permuted within 64B
  int srow = tid >> 2;                               // 0..127
  int scol = ((tid & 3) ^ ((tid >> 3) & 3)) * 16;    // permuted 16B chunk
  int sdst = tid * 16;                               // linear dest byte offset

  // read bases with matching chunk xor: data (row=lr, k16) lives at
  // row*64 + (k16 ^ ((row>>1)&3))*16; fragment offsets are immediates.
  int cxA = (k16 ^ ((lr >> 1) & 3)) * 16;
  uint32_t aOff = (uint32_t)(uintptr_t)(lds_i8*)&sA[0][(wm * 128 + lr) * 64 + cxA];
  uint32_t bOff = (uint32_t)(uintptr_t)(lds_i8*)&sB[0][(bh * 128 + bq * 64 + lr) * 64 + cxA];

  i32x4 acc[8][4] = {};
  f32x4 aP[4], aQ[4], bE[4], bO[4];

  // prologue: tiles 0 (buf0) + 1 (buf1) staged; retire tile0 (VM4 keeps
  // tile1's 4 in flight, gated at first ph2); publish; pre-read ph1 frags.
  STAGE_A(0, 0); STAGE_B(0, 0);
  STAGE_A(1, 64); STAGE_B(1, 64);
  VM4; BAR;
  READ_AQ(aP, 0, 0); READ_B4(bE, 0);   // drained by ph1's LGKM(4)

#pragma unroll 1
  for (int i = 0; i < NIT - 1; ++i) {
    ITER(i * 128, 1, 1);
  }
  ITER((NIT - 1) * 128, 0, 0);   // tiles 22,23: no stages/read-ahead

  // epilogue: per-row min over this tile's 256 cols of (bn - 2*sq*sb*idot)
  float bnv[4], bsv[4];
#pragma unroll
  for (int n_ = 0; n_ < 4; ++n_) {
    int col = nt * 256 + wn * 64 + n_ * 16 + lr;
    bnv[n_] = bn[col];
    bsv[n_] = 2.0f * bscale[col];
  }
  int qbase = mt * 256 + wm * 128;
#pragma unroll
  for (int m_ = 0; m_ < 8; ++m_) {
    f32x4 sq = *(const f32x4*)&qscale[qbase + m_ * 16 + (lane >> 4) * 4];
#pragma unroll
    for (int r = 0; r < 4; ++r) {
      float sqr = sq[r];
      float v =          bnv[0] - bsv[0] * sqr * (float)acc[m_][0][r];
      v = fminf(v, bnv[1] - bsv[1] * sqr * (float)acc[m_][1][r]);
      v = fminf(v, bnv[2] - bsv[2] * sqr * (float)acc[m_][2][r]);
      v = fminf(v, bnv[3] - bsv[3] * sqr * (float)acc[m_][3][r]);
      // C/D layout (shape-determined): col = lane&15, row = (lane>>4)*4+r
      v = fminf(v, __shfl_xor(v, 1));
      v = fminf(v, __shfl_xor(v, 2));
      v = fminf(v, __shfl_xor(v, 4));
      v = fminf(v, __shfl_xor(v, 8));
      if (lr == 0) {
        int q = qbase + m_ * 16 + (lane >> 4) * 4 + r;
        atomicMin(&minbits[q], __float_as_uint(v));  // positive floats: uint order == float order
      }
    }
  }
}

// ---- patch scores + per-image max -------------------------------------
__global__ void scores_kernel(const uint32_t* __restrict__ minbits, const float* __restrict__ qn,
                              float* __restrict__ ps, float* __restrict__ img) {
  int q = blockIdx.x * 256 + threadIdx.x;
  if (q >= NQ) return;
  float s = __uint_as_float(minbits[q]) + qn[q];
  ps[q] = s;
  atomicMax((uint32_t*)&img[q / 784], __float_as_uint(s));  // scores > 0
}

// ---- bilinear 28x28 -> 224x224 (half-pixel centers, edge clamp) -------
__global__ void resize_kernel(const float* __restrict__ ps, float* __restrict__ masks) {
  int idx = blockIdx.x * 256 + threadIdx.x;
  if (idx >= NPIX) return;
  int b   = idx / (224 * 224);
  int rem = idx - b * (224 * 224);
  int oy  = rem / 224;
  int ox  = rem - oy * 224;
  float sy = (oy + 0.5f) * 0.125f - 0.5f;
  float sx = (ox + 0.5f) * 0.125f - 0.5f;
  float fy0 = floorf(sy), fx0 = floorf(sx);
  int y0 = (int)fy0, x0 = (int)fx0;
  float fy = sy - fy0, fx = sx - fx0;
  int y0c = min(max(y0, 0), 27),     y1c = min(max(y0 + 1, 0), 27);
  int x0c = min(max(x0, 0), 27),     x1c = min(max(x0 + 1, 0), 27);
  const float* p = ps + b * 784;
  float top = p[y0c * 28 + x0c] * (1.f - fx) + p[y0c * 28 + x1c] * fx;
  float bot = p[y1c * 28 + x0c] * (1.f - fx) + p[y1c * 28 + x1c] * fx;
  masks[idx] = top * (1.f - fy) + bot * fy;
}

// ---- host launch -------------------------------------------------------
extern "C" void kernel_launch(void* const* d_in, const int* in_sizes, int n_in,
                              void* d_out, int out_size, void* d_ws, size_t ws_size,
                              hipStream_t stream) {
  const float* features = (const float*)d_in[0];   // [6272, 1536]
  const float* bank     = (const float*)d_in[1];   // [50000, 1536]

  char* ws = (char*)d_ws;
  size_t off = 0;
  signed char* bankQ = (signed char*)(ws + off); off += (size_t)NBP2 * DIM;   // 77.1 MB
  signed char* featQ = (signed char*)(ws + off); off += (size_t)NQP * DIM;    //  9.8 MB
  float*    bn      = (float*)(ws + off);    off += (size_t)NBP2 * 4;
  float*    qn      = (float*)(ws + off);    off += (size_t)NQP * 4;
  float*    bscale  = (float*)(ws + off);    off += (size_t)NBP2 * 4;
  float*    qscale  = (float*)(ws + off);    off += (size_t)NQP * 4;
  uint32_t* minbits = (uint32_t*)(ws + off); off += (size_t)NQP * 4;
  float*    ps      = (float*)(ws + off);    off += (size_t)NQ * 4;

  float* out_scores = (float*)d_out;       // [8]
  float* masks      = out_scores + 8;      // [8,224,224]

  hipLaunchKernelGGL(init_kernel, dim3(25), dim3(256), 0, stream, minbits, out_scores);
  hipLaunchKernelGGL(quant_rows, dim3(NBP2 / 4), dim3(256), 0, stream, bank, bankQ, bn, bscale, NB, NBP2);
  hipLaunchKernelGGL(quant_rows, dim3(NQP / 4), dim3(256), 0, stream, features, featQ, qn, qscale, NQ, NQP);
  hipLaunchKernelGGL(gemm_min8, dim3(GRID2), dim3(512), 0, stream, featQ, bankQ, bn, bscale, qscale, minbits);
  hipLaunchKernelGGL(scores_kernel, dim3(25), dim3(256), 0, stream, minbits, qn, ps, out_scores);
  hipLaunchKernelGGL(resize_kernel, dim3((NPIX + 255) / 256), dim3(256), 0, stream, ps, masks);
}

// Round 16
// 701.283 us; speedup vs baseline: 1.1275x; 1.0044x over previous
//
#include <hip/hip_runtime.h>
#include <stdint.h>

// ---- Problem constants -------------------------------------------------
#define DIM   1536
#define NQ    6272      // 8 * 28 * 28 queries
#define NQP   6400      // padded to 25 * 256
#define NB    50000     // bank rows
#define NBP2  50176     // padded to 196 * 256
#define MT2   25
#define NT2   196
#define GRID2 (MT2 * NT2)
#define NKT   24        // 1536 / 64 K-tiles
#define NIT   12        // NKT / 2 iterations
#define NPIX  (8 * 224 * 224)

typedef float f32x4 __attribute__((ext_vector_type(4)));
typedef int   i32x4 __attribute__((ext_vector_type(4)));
typedef __attribute__((address_space(3))) signed char lds_i8;

__device__ inline void gll16(const signed char* g, signed char* l) {
  __builtin_amdgcn_global_load_lds(
      (const __attribute__((address_space(1))) uint32_t*)g,
      (__attribute__((address_space(3))) uint32_t*)l, 16, 0, 0);
}

// ---- init: minbits = +inf, image scores = 0 ---------------------------
__global__ void init_kernel(uint32_t* __restrict__ minbits, float* __restrict__ out_scores) {
  int i = blockIdx.x * 256 + threadIdx.x;
  if (i < NQP) minbits[i] = 0x7F800000u;   // +inf
  if (i < 8)   out_scores[i] = 0.0f;
}

// ---- fp32 -> int8 row quantization + fp32 row norms + scales ----------
// one wave per row; scale = maxabs/127; norm from ORIGINAL fp32 values.
__global__ void quant_rows(const float* __restrict__ src, signed char* __restrict__ dst,
                           float* __restrict__ norms, float* __restrict__ scales,
                           int nsrc, int ndst) {
  int row  = blockIdx.x * 4 + (threadIdx.x >> 6);
  int lane = threadIdx.x & 63;
  if (row >= ndst) return;
  uint32_t* drow = (uint32_t*)(dst + (size_t)row * DIM);
  if (row < nsrc) {
    const float4* s = (const float4*)(src + (size_t)row * DIM);
    float4 v[6]; float ns = 0.f, mx = 0.f;
#pragma unroll
    for (int i = 0; i < 6; ++i) {
      v[i] = s[lane + 64 * i];
      ns += v[i].x * v[i].x + v[i].y * v[i].y + v[i].z * v[i].z + v[i].w * v[i].w;
      mx = fmaxf(mx, fmaxf(fmaxf(fabsf(v[i].x), fabsf(v[i].y)),
                           fmaxf(fabsf(v[i].z), fabsf(v[i].w))));
    }
#pragma unroll
    for (int off = 32; off >= 1; off >>= 1) {
      ns += __shfl_xor(ns, off);
      mx = fmaxf(mx, __shfl_xor(mx, off));
    }
    float inv = (mx > 0.f) ? 127.0f / mx : 0.f;
#pragma unroll
    for (int i = 0; i < 6; ++i) {
      int a = max(-127, min(127, __float2int_rn(v[i].x * inv)));
      int b = max(-127, min(127, __float2int_rn(v[i].y * inv)));
      int c = max(-127, min(127, __float2int_rn(v[i].z * inv)));
      int d = max(-127, min(127, __float2int_rn(v[i].w * inv)));
      drow[lane + 64 * i] = (uint32_t)(a & 255) | ((uint32_t)(b & 255) << 8) |
                            ((uint32_t)(c & 255) << 16) | ((uint32_t)(d & 255) << 24);
    }
    if (lane == 0) { norms[row] = ns; scales[row] = mx * (1.0f / 127.0f); }
  } else {
#pragma unroll
    for (int i = 0; i < 6; ++i) drow[lane + 64 * i] = 0u;
    if (lane == 0) { norms[row] = 1e30f; scales[row] = 0.f; }   // pad never wins
  }
}

// ---- fused 256x256 int8 GEMM + column-min -----------------------------
// BM=BN=256, BK=64, 512 thr = 8 waves (2M x 4N), per-wave 128x64 out.
// mfma_i32_16x16x64_i8; chunk-XOR swizzled 64B-row LDS (R15, 0 conflicts).
// EVEN READ SCHEDULE: 4/4/2/2/4/4/2/2 ds_read_b128 per phase, every read
// exactly 2 phases before its MFMA; LGKM counts 6/8/2/4 cover only reads
// >=2 phases old (service window ~2 phases >> 384 cyc burst) -> no LGKM
// stalls. Gates: VM2 at ph2/4/6/8, each publishing the stage issued 2
// phases earlier. ph3/ph7 LGKM(2) drains ALL waves' tile readers before
// the barrier preceding ph4/ph8 stages (cross-wave WAR closed by barrier
// ordering). Phase order: [reads; LGKM; stage+gate; BAR; MFMA].
#define BAR   do { asm volatile("s_barrier" ::: "memory"); \
                   __builtin_amdgcn_sched_barrier(0); } while(0)
#define LGKM(n) do { asm volatile("s_waitcnt lgkmcnt(" #n ")" ::: "memory"); \
                     __builtin_amdgcn_sched_barrier(0); } while(0)
#define VM0   asm volatile("s_waitcnt vmcnt(0)" ::: "memory")
#define VM2   asm volatile("s_waitcnt vmcnt(2)" ::: "memory")
#define PHI   __builtin_amdgcn_s_setprio(1)
#define PLO   __builtin_amdgcn_s_setprio(0)

#define DSR(dst, base, imm) \
  asm volatile("ds_read_b128 %0, %1 offset:%2" : "=v"(dst) : "v"(base), "i"(imm))

// two A m-fragments (frag, frag+1) of buf -> dst[i0], dst[i0+1]
#define RD_A2(dst, i0, bufI, frag) do { \
  DSR(dst[i0],       aOff, (bufI) * 16384 + (frag) * 1024);       \
  DSR(dst[(i0) + 1], aOff, (bufI) * 16384 + ((frag) + 1) * 1024); \
} while(0)

// two B n-fragments (frag, frag+1) of buf
#define RD_B2(dst, i0, bufI, frag) do { \
  DSR(dst[i0],       bOff, (bufI) * 16384 + (frag) * 1024);       \
  DSR(dst[(i0) + 1], bOff, (bufI) * 16384 + ((frag) + 1) * 1024); \
} while(0)

// 8 MFMA: m-pair (mb, mb+1) x 4 n, K=64
#define MFMA8(mb, x0, x1, b4) do { \
  _Pragma("unroll") for (int n_ = 0; n_ < 4; ++n_) { \
    acc[(mb)][n_]     = __builtin_amdgcn_mfma_i32_16x16x64_i8( \
      __builtin_bit_cast(i32x4, (x0)), __builtin_bit_cast(i32x4, b4[n_]), acc[(mb)][n_], 0, 0, 0); \
    acc[(mb) + 1][n_] = __builtin_amdgcn_mfma_i32_16x16x64_i8( \
      __builtin_bit_cast(i32x4, (x1)), __builtin_bit_cast(i32x4, b4[n_]), acc[(mb) + 1][n_], 0, 0, 0); \
  } \
} while(0)

// stage one 256x64 i8 tile (16 KB) = 2 gll16/thread; dest linear,
// source: row = tid>>2 (coalesced 64B segments), chunk permuted by
// (tid&3) ^ ((tid>>3)&3) = c ^ ((row>>1)&3). Row+128 has same xor term.
#define STAGE_A(bufI, ktc) do { \
  const signed char* _g = gA + (size_t)srow * DIM + (ktc) + scol; \
  gll16(_g,                      &sA[bufI][sdst]); \
  gll16(_g + (size_t)128 * DIM,  &sA[bufI][8192 + sdst]); \
} while(0)

#define STAGE_B(bufI, ktc) do { \
  const signed char* _g = gB + (size_t)srow * DIM + (ktc) + scol; \
  gll16(_g,                      &sB[bufI][sdst]); \
  gll16(_g + (size_t)128 * DIM,  &sB[bufI][8192 + sdst]); \
} while(0)

// iter i: tiles t0=2i (buf0, ph1-4) + t1=2i+1 (buf1, ph5-8); T0 = i*128.
// Reads (frag pairs, 2-phase-ahead): ph1 aQ01(buf0,f4)+bO01(buf1,f0);
// ph2 aQ23(f6)+bO23(f2); ph3 aP01(buf1,f0); ph4 aP23(buf1,f2);
// ph5 aQ01(buf1,f4)+bE01(buf0',f0); ph6 aQ23(buf1,f6)+bE23(buf0',f2);
// ph7 aP01(buf0',f0); ph8 aP23(buf0',f2).
// Stages: ph2 B(buf0,t+2), ph4 A(buf0,t+2), ph6 B(buf1,t+3), ph8 A(buf1,t+3);
// gate VM2 after each (publishes the stage from 2 phases earlier).
#define ITER(T0, SN, TAIL) do { \
  /* ph1 */ RD_A2(aQ, 0, 0, 4); RD_B2(bO, 0, 1, 0); \
    LGKM(6); BAR; PHI; MFMA8(0, aP[0], aP[1], bE); PLO; \
  /* ph2 */ RD_A2(aQ, 2, 0, 6); RD_B2(bO, 2, 1, 2); \
    LGKM(8); \
    if (SN) { STAGE_B(0, (T0) + 128); VM2; } else { VM0; } \
    BAR; PHI; MFMA8(2, aP[2], aP[3], bE); PLO; \
  /* ph3 */ RD_A2(aP, 0, 1, 0); \
    LGKM(2); BAR; PHI; MFMA8(4, aQ[0], aQ[1], bE); PLO; \
  /* ph4 */ RD_A2(aP, 2, 1, 2); \
    LGKM(4); \
    if (SN) { STAGE_A(0, (T0) + 128); VM2; } \
    BAR; PHI; MFMA8(6, aQ[2], aQ[3], bE); PLO; \
  /* ph5 */ RD_A2(aQ, 0, 1, 4); \
    if (!TAIL) { RD_B2(bE, 0, 0, 0); LGKM(6); } else { LGKM(4); } \
    BAR; PHI; MFMA8(0, aP[0], aP[1], bO); PLO; \
  /* ph6 */ RD_A2(aQ, 2, 1, 6); \
    if (!TAIL) { RD_B2(bE, 2, 0, 2); LGKM(8); } else { LGKM(4); } \
    if (SN) { STAGE_B(1, (T0) + 192); VM2; } \
    BAR; PHI; MFMA8(2, aP[2], aP[3], bO); PLO; \
  /* ph7 */ if (!TAIL) { RD_A2(aP, 0, 0, 0); } \
    LGKM(2); BAR; PHI; MFMA8(4, aQ[0], aQ[1], bO); PLO; \
  /* ph8 */ if (!TAIL) { RD_A2(aP, 2, 0, 2); LGKM(4); } else { LGKM(0); } \
    if (SN) { STAGE_A(1, (T0) + 192); VM2; } \
    BAR; PHI; MFMA8(6, aQ[2], aQ[3], bO); PLO; \
} while(0)

__global__ __launch_bounds__(512, 2)
void gemm_min8(const signed char* __restrict__ fA, const signed char* __restrict__ bB,
               const float* __restrict__ bn, const float* __restrict__ bscale,
               const float* __restrict__ qscale, uint32_t* __restrict__ minbits) {
  __shared__ __align__(16) signed char sA[2][16384];   // [buf][256 rows][64] = 32 KiB
  __shared__ __align__(16) signed char sB[2][16384];   // 32 KiB

  const int nwg = GRID2;
  int bid = blockIdx.x;
  const int qch = nwg >> 3, rch = nwg & 7;
  int xcd = bid & 7, loc = bid >> 3;
  int swz = (xcd < rch ? xcd * (qch + 1) : rch * (qch + 1) + (xcd - rch) * qch) + loc;
  int mt = swz % MT2;            // M-fast: consecutive blocks share the B (bank) panel
  int nt = swz / MT2;

  int tid = threadIdx.x;
  int lane = tid & 63, wave = tid >> 6;
  int wm = wave >> 2, wn = wave & 3, bq = wn & 1, bh = wn >> 1;
  int lr = lane & 15, k16 = lane >> 4;

  const signed char* gA = fA + (size_t)(mt * 256) * DIM;
  const signed char* gB = bB + (size_t)(nt * 256) * DIM;

  // staging: row = tid>>2 (coalesced), chunk xor-permuted within 64B
  int srow = tid >> 2;                               // 0..127
  int scol = ((tid & 3) ^ ((tid >> 3) & 3)) * 16;    // permuted 16B chunk
  int sdst = tid * 16;                               // linear dest byte offset

  // read bases with matching chunk xor: data (row=lr, k16) lives at
  // row*64 + (k16 ^ ((row>>1)&3))*16; fragment offsets are immediates.
  int cxA = (k16 ^ ((lr >> 1) & 3)) * 16;
  uint32_t aOff = (uint32_t)(uintptr_t)(lds_i8*)&sA[0][(wm * 128 + lr) * 64 + cxA];
  uint32_t bOff = (uint32_t)(uintptr_t)(lds_i8*)&sB[0][(bh * 128 + bq * 64 + lr) * 64 + cxA];

  i32x4 acc[8][4] = {};
  f32x4 aP[4], aQ[4], bE[4], bO[4];

  // prologue: stage tiles 0 (buf0 A+B) and 1 (buf1 B then A); VM2 retires
  // all but A(1) (= steady-state "prev ph8 stage"); publish; pre-read bE
  // (buf0 B) then aP (buf0 f0-3) -- ph1's LGKM(6) keeps only aP[2:3].
  STAGE_A(0, 0); STAGE_B(0, 0);
  STAGE_B(1, 64); STAGE_A(1, 64);
  VM2; BAR;
  RD_B2(bE, 0, 0, 0); RD_B2(bE, 2, 0, 2);
  RD_A2(aP, 0, 0, 0); RD_A2(aP, 2, 0, 2);

#pragma unroll 1
  for (int i = 0; i < NIT - 1; ++i) {
    ITER(i * 128, 1, 0);
  }
  ITER((NIT - 1) * 128, 0, 1);   // tiles 22,23: no stages, no next-iter reads

  // epilogue: per-row min over this tile's 256 cols of (bn - 2*sq*sb*idot)
  float bnv[4], bsv[4];
#pragma unroll
  for (int n_ = 0; n_ < 4; ++n_) {
    int col = nt * 256 + wn * 64 + n_ * 16 + lr;
    bnv[n_] = bn[col];
    bsv[n_] = 2.0f * bscale[col];
  }
  int qbase = mt * 256 + wm * 128;
#pragma unroll
  for (int m_ = 0; m_ < 8; ++m_) {
    f32x4 sq = *(const f32x4*)&qscale[qbase + m_ * 16 + (lane >> 4) * 4];
#pragma unroll
    for (int r = 0; r < 4; ++r) {
      float sqr = sq[r];
      float v =          bnv[0] - bsv[0] * sqr * (float)acc[m_][0][r];
      v = fminf(v, bnv[1] - bsv[1] * sqr * (float)acc[m_][1][r]);
      v = fminf(v, bnv[2] - bsv[2] * sqr * (float)acc[m_][2][r]);
      v = fminf(v, bnv[3] - bsv[3] * sqr * (float)acc[m_][3][r]);
      // C/D layout (shape-determined): col = lane&15, row = (lane>>4)*4+r
      v = fminf(v, __shfl_xor(v, 1));
      v = fminf(v, __shfl_xor(v, 2));
      v = fminf(v, __shfl_xor(v, 4));
      v = fminf(v, __shfl_xor(v, 8));
      if (lr == 0) {
        int q = qbase + m_ * 16 + (lane >> 4) * 4 + r;
        atomicMin(&minbits[q], __float_as_uint(v));  // positive floats: uint order == float order
      }
    }
  }
}

// ---- patch scores + per-image max -------------------------------------
__global__ void scores_kernel(const uint32_t* __restrict__ minbits, const float* __restrict__ qn,
                              float* __restrict__ ps, float* __restrict__ img) {
  int q = blockIdx.x * 256 + threadIdx.x;
  if (q >= NQ) return;
  float s = __uint_as_float(minbits[q]) + qn[q];
  ps[q] = s;
  atomicMax((uint32_t*)&img[q / 784], __float_as_uint(s));  // scores > 0
}

// ---- bilinear 28x28 -> 224x224 (half-pixel centers, edge clamp) -------
__global__ void resize_kernel(const float* __restrict__ ps, float* __restrict__ masks) {
  int idx = blockIdx.x * 256 + threadIdx.x;
  if (idx >= NPIX) return;
  int b   = idx / (224 * 224);
  int rem = idx - b * (224 * 224);
  int oy  = rem / 224;
  int ox  = rem - oy * 224;
  float sy = (oy + 0.5f) * 0.125f - 0.5f;
  float sx = (ox + 0.5f) * 0.125f - 0.5f;
  float fy0 = floorf(sy), fx0 = floorf(sx);
  int y0 = (int)fy0, x0 = (int)fx0;
  float fy = sy - fy0, fx = sx - fx0;
  int y0c = min(max(y0, 0), 27),     y1c = min(max(y0 + 1, 0), 27);
  int x0c = min(max(x0, 0), 27),     x1c = min(max(x0 + 1, 0), 27);
  const float* p = ps + b * 784;
  float top = p[y0c * 28 + x0c] * (1.f - fx) + p[y0c * 28 + x1c] * fx;
  float bot = p[y1c * 28 + x0c] * (1.f - fx) + p[y1c * 28 + x1c] * fx;
  masks[idx] = top * (1.f - fy) + bot * fy;
}

// ---- host launch -------------------------------------------------------
extern "C" void kernel_launch(void* const* d_in, const int* in_sizes, int n_in,
                              void* d_out, int out_size, void* d_ws, size_t ws_size,
                              hipStream_t stream) {
  const float* features = (const float*)d_in[0];   // [6272, 1536]
  const float* bank     = (const float*)d_in[1];   // [50000, 1536]

  char* ws = (char*)d_ws;
  size_t off = 0;
  signed char* bankQ = (signed char*)(ws + off); off += (size_t)NBP2 * DIM;   // 77.1 MB
  signed char* featQ = (signed char*)(ws + off); off += (size_t)NQP * DIM;    //  9.8 MB
  float*    bn      = (float*)(ws + off);    off += (size_t)NBP2 * 4;
  float*    qn      = (float*)(ws + off);    off += (size_t)NQP * 4;
  float*    bscale  = (float*)(ws + off);    off += (size_t)NBP2 * 4;
  float*    qscale  = (float*)(ws + off);    off += (size_t)NQP * 4;
  uint32_t* minbits = (uint32_t*)(ws + off); off += (size_t)NQP * 4;
  float*    ps      = (float*)(ws + off);    off += (size_t)NQ * 4;

  float* out_scores = (float*)d_out;       // [8]
  float* masks      = out_scores + 8;      // [8,224,224]

  hipLaunchKernelGGL(init_kernel, dim3(25), dim3(256), 0, stream, minbits, out_scores);
  hipLaunchKernelGGL(quant_rows, dim3(NBP2 / 4), dim3(256), 0, stream, bank, bankQ, bn, bscale, NB, NBP2);
  hipLaunchKernelGGL(quant_rows, dim3(NQP / 4), dim3(256), 0, stream, features, featQ, qn, qscale, NQ, NQP);
  hipLaunchKernelGGL(gemm_min8, dim3(GRID2), dim3(512), 0, stream, featQ, bankQ, bn, bscale, qscale, minbits);
  hipLaunchKernelGGL(scores_kernel, dim3(25), dim3(256), 0, stream, minbits, qn, ps, out_scores);
  hipLaunchKernelGGL(resize_kernel, dim3((NPIX + 255) / 256), dim3(256), 0, stream, ps, masks);
}